// Round 2
// baseline (462.193 us; speedup 1.0000x reference)
//
#include <hip/hip_runtime.h>
#include <cstdint>
#include <cstddef>

// Problem constants
#define B_    8
#define C_    256
#define H_    64
#define W_    64
#define A_    4
#define NH_   8
#define DH_   32
#define L_    1024
#define NPAIR 32
#define QKVN  768

typedef __bf16 bf16;
typedef __bf16 bf16x8 __attribute__((ext_vector_type(8)));
typedef __bf16 bf16x4 __attribute__((ext_vector_type(4)));
typedef float  f32x4  __attribute__((ext_vector_type(4)));

__device__ inline f32x4 mfma16(bf16x8 a, bf16x8 b, f32x4 c) {
    return __builtin_amdgcn_mfma_f32_16x16x32_bf16(a, b, c, 0, 0, 0);
}
__device__ inline bf16x8 ld8(const bf16* p) { return *(const bf16x8*)p; }

// ---------------------------------------------------------------------------
// K_CVT: convert W_in (4*768*256 f32) and W_out (4*256*256 f32) to bf16
// ---------------------------------------------------------------------------
#define NW4 (786432 / 4)
#define NO4 (262144 / 4)
__global__ __launch_bounds__(256) void k_cvt(const float* __restrict__ Win,
                                             const float* __restrict__ Wout,
                                             bf16* __restrict__ Winb,
                                             bf16* __restrict__ Woutb) {
    int tid = blockIdx.x * 256 + threadIdx.x;
    if (tid < NW4) {
        float4 v = ((const float4*)Win)[tid];
        bf16x4 ov = {(bf16)v.x, (bf16)v.y, (bf16)v.z, (bf16)v.w};
        ((bf16x4*)Winb)[tid] = ov;
    } else if (tid < NW4 + NO4) {
        int t2 = tid - NW4;
        float4 v = ((const float4*)Wout)[t2];
        bf16x4 ov = {(bf16)v.x, (bf16)v.y, (bf16)v.z, (bf16)v.w};
        ((bf16x4*)Woutb)[t2] = ov;
    }
}

// ---------------------------------------------------------------------------
// K0: x[B,C,H,W] (f32) -> xa[pair, l, c] (bf16)   pair = b*4+i*2+j, l = p*32+q
// ---------------------------------------------------------------------------
__global__ __launch_bounds__(256) void k_split(const float* __restrict__ x,
                                               bf16* __restrict__ xa) {
    __shared__ float lds[32][257];
    int bid = blockIdx.x;
    int pair = bid >> 5, p = bid & 31;
    int b = pair >> 2, a = pair & 3, i = a >> 1, j = a & 1;
    int t = threadIdx.x;
    int q = t & 31, csub = t >> 5;
    const float* xb = x + (size_t)b * C_ * H_ * W_ + (size_t)(i * 32 + p) * W_ + j * 32;
    for (int r = 0; r < 32; ++r) {
        int c = r * 8 + csub;
        lds[q][c] = xb[(size_t)c * H_ * W_ + q];
    }
    __syncthreads();
    bf16* xr = xa + ((size_t)pair * L_ + (size_t)p * 32) * C_;
    for (int r = 0; r < 32; ++r) {
        xr[(size_t)r * C_ + t] = (bf16)lds[r][t];
    }
}

// ---------------------------------------------------------------------------
// K1: qkv[pair, l, 768] = xa[pair] @ W_in[a]^T + b_in[a]   (bf16 out)
// grid: pair(32) x mt(16) x nt(6); block 256 (4 waves, 16 rows each)
// ---------------------------------------------------------------------------
__global__ __launch_bounds__(256) void k_qkv(const bf16* __restrict__ xa,
                                             const bf16* __restrict__ Win,
                                             const float* __restrict__ bin,
                                             bf16* __restrict__ qkv) {
    int bid = blockIdx.x;
    int nt = bid % 6, mt = (bid / 6) & 15, pair = bid / 96;
    int a = pair & 3;
    int t = threadIdx.x, w = t >> 6, lane = t & 63, quad = lane >> 4, l16 = lane & 15;
    int m0 = mt * 64 + w * 16;
    int n0 = nt * 128;
    f32x4 acc[8];
#pragma unroll
    for (int u = 0; u < 8; ++u) acc[u] = (f32x4){0.f, 0.f, 0.f, 0.f};
    const bf16* arow  = xa + ((size_t)pair * L_ + m0 + l16) * C_ + quad * 8;
    const bf16* bbase = Win + (size_t)a * QKVN * C_ + quad * 8;
#pragma unroll
    for (int k0 = 0; k0 < C_; k0 += 32) {
        bf16x8 af = ld8(arow + k0);
#pragma unroll
        for (int u = 0; u < 8; ++u) {
            bf16x8 bfr = ld8(bbase + (size_t)(n0 + u * 16 + l16) * C_ + k0);
            acc[u] = mfma16(af, bfr, acc[u]);
        }
    }
    bf16* obase = qkv + (size_t)pair * L_ * QKVN;
#pragma unroll
    for (int u = 0; u < 8; ++u) {
        int col = n0 + u * 16 + l16;
        float bias = bin[a * QKVN + col];
#pragma unroll
        for (int r = 0; r < 4; ++r) {
            int row = m0 + quad * 4 + r;
            obase[(size_t)row * QKVN + col] = (bf16)(acc[u][r] + bias);
        }
    }
}

// ---------------------------------------------------------------------------
// K2: flash attention per (pair, head, 64-row Q tile). block 256 = 4 waves.
// q at col 0, k at col 256, v at col 512 of qkv rows. o[pair, l, 256] bf16.
// ---------------------------------------------------------------------------
__global__ __launch_bounds__(256) void k_attn(const bf16* __restrict__ qkv,
                                              bf16* __restrict__ o) {
    __shared__ __align__(16) bf16 vt[32][72];      // V^T tile: [e][kv]
    __shared__ __align__(16) bf16 pl[4][16][72];   // P tile per wave: [q][kv]
    int bid = blockIdx.x;
    int qt = bid & 15, head = (bid >> 4) & 7, pair = bid >> 7;
    int t = threadIdx.x, w = t >> 6, lane = t & 63, quad = lane >> 4, l16 = lane & 15;
    const bf16* base = qkv + (size_t)pair * L_ * QKVN;
    const bf16* qptr = base + head * DH_;
    const bf16* kptr = base + C_ + head * DH_;
    const bf16* vptr = base + 2 * C_ + head * DH_;
    int q0 = qt * 64 + w * 16;
    bf16x8 qf = ld8(qptr + (size_t)(q0 + l16) * QKVN + quad * 8);
    float m_r[4], l_r[4], alpha[4];
    f32x4 acc0 = {0.f, 0.f, 0.f, 0.f}, acc1 = {0.f, 0.f, 0.f, 0.f};
#pragma unroll
    for (int r = 0; r < 4; ++r) { m_r[r] = -1e30f; l_r[r] = 0.f; }
    const float sc = 0.17677669529663687f;  // dh^-0.5
    int vkv = t >> 2, ve0 = (t & 3) * 8;
    for (int kv0 = 0; kv0 < L_; kv0 += 64) {
        // stage V^T tile cooperatively
        {
            bf16x8 vv = ld8(vptr + (size_t)(kv0 + vkv) * QKVN + ve0);
#pragma unroll
            for (int u = 0; u < 8; ++u) vt[ve0 + u][vkv] = vv[u];
        }
        __syncthreads();
        // scores: 4 mfmas -> S[16q x 64kv] in C/D layout
        f32x4 s[4];
#pragma unroll
        for (int kb = 0; kb < 4; ++kb) {
            bf16x8 kf = ld8(kptr + (size_t)(kv0 + kb * 16 + l16) * QKVN + quad * 8);
            s[kb] = mfma16(qf, kf, (f32x4){0.f, 0.f, 0.f, 0.f});
        }
        // online softmax per row (row = quad*4 + r; 16 lanes of quad share it)
#pragma unroll
        for (int r = 0; r < 4; ++r) {
            float bm = fmaxf(fmaxf(s[0][r], s[1][r]), fmaxf(s[2][r], s[3][r]));
#pragma unroll
            for (int off = 1; off < 16; off <<= 1) bm = fmaxf(bm, __shfl_xor(bm, off));
            float nm = fmaxf(m_r[r], bm);
            alpha[r] = __expf(sc * (m_r[r] - nm));
            m_r[r] = nm;
            float rs = 0.f;
#pragma unroll
            for (int kb = 0; kb < 4; ++kb) {
                float pv = __expf(sc * (s[kb][r] - nm));
                s[kb][r] = pv;
                rs += pv;
            }
#pragma unroll
            for (int off = 1; off < 16; off <<= 1) rs += __shfl_xor(rs, off);
            l_r[r] = l_r[r] * alpha[r] + rs;
        }
#pragma unroll
        for (int r = 0; r < 4; ++r) { acc0[r] *= alpha[r]; acc1[r] *= alpha[r]; }
        // P: C/D layout -> LDS -> A layout (per-wave private region, in-wave order)
#pragma unroll
        for (int kb = 0; kb < 4; ++kb)
#pragma unroll
            for (int r = 0; r < 4; ++r)
                pl[w][quad * 4 + r][kb * 16 + l16] = (bf16)s[kb][r];
#pragma unroll
        for (int ks = 0; ks < 2; ++ks) {
            bf16x8 pf = *(const bf16x8*)&pl[w][l16][ks * 32 + quad * 8];
            bf16x8 v0 = *(const bf16x8*)&vt[l16][ks * 32 + quad * 8];
            bf16x8 v1 = *(const bf16x8*)&vt[16 + l16][ks * 32 + quad * 8];
            acc0 = mfma16(pf, v0, acc0);
            acc1 = mfma16(pf, v1, acc1);
        }
        __syncthreads();
    }
    bf16* orow = o + (size_t)pair * L_ * C_ + head * DH_;
#pragma unroll
    for (int r = 0; r < 4; ++r) {
        float inv = 1.f / l_r[r];
        int row = q0 + quad * 4 + r;
        orow[(size_t)row * C_ + l16]      = (bf16)(acc0[r] * inv);
        orow[(size_t)row * C_ + 16 + l16] = (bf16)(acc1[r] * inv);
    }
}

// ---------------------------------------------------------------------------
// K3: y = LayerNorm(o @ W_out[a]^T + b_out[a] + xa) * gamma + beta  (f32 out)
// grid: pair(32) x mt(16); block 256; each block: 64 rows x full 256 cols
// ---------------------------------------------------------------------------
__global__ __launch_bounds__(256) void k_out(const bf16* __restrict__ o,
                                             const bf16* __restrict__ Wout,
                                             const float* __restrict__ bout,
                                             const bf16* __restrict__ xa,
                                             const float* __restrict__ gamma,
                                             const float* __restrict__ beta,
                                             float* __restrict__ y) {
    int bid = blockIdx.x;
    int mt = bid & 15, pair = bid >> 4;
    int a = pair & 3;
    int t = threadIdx.x, w = t >> 6, lane = t & 63, quad = lane >> 4, l16 = lane & 15;
    int m0 = mt * 64 + w * 16;
    f32x4 acc[16];
#pragma unroll
    for (int u = 0; u < 16; ++u) acc[u] = (f32x4){0.f, 0.f, 0.f, 0.f};
    const bf16* arow  = o + ((size_t)pair * L_ + m0 + l16) * C_ + quad * 8;
    const bf16* bbase = Wout + (size_t)a * C_ * C_ + quad * 8;
#pragma unroll
    for (int k0 = 0; k0 < C_; k0 += 32) {
        bf16x8 af = ld8(arow + k0);
#pragma unroll
        for (int u = 0; u < 16; ++u) {
            bf16x8 bfr = ld8(bbase + (size_t)(u * 16 + l16) * C_ + k0);
            acc[u] = mfma16(af, bfr, acc[u]);
        }
    }
    // bias + residual
    const bf16* xrow = xa + ((size_t)pair * L_ + m0) * C_;
#pragma unroll
    for (int u = 0; u < 16; ++u) {
        int col = u * 16 + l16;
        float bias = bout[a * C_ + col];
#pragma unroll
        for (int r = 0; r < 4; ++r)
            acc[u][r] += bias + (float)xrow[(size_t)(quad * 4 + r) * C_ + col];
    }
    // LayerNorm over 256 cols per row (in-lane 16 + shfl over 16 lanes)
    float mu[4], rstd[4];
#pragma unroll
    for (int r = 0; r < 4; ++r) {
        float s1 = 0.f;
#pragma unroll
        for (int u = 0; u < 16; ++u) s1 += acc[u][r];
#pragma unroll
        for (int off = 1; off < 16; off <<= 1) s1 += __shfl_xor(s1, off);
        float m = s1 * (1.f / 256.f);
        float s2 = 0.f;
#pragma unroll
        for (int u = 0; u < 16; ++u) { float d = acc[u][r] - m; s2 += d * d; }
#pragma unroll
        for (int off = 1; off < 16; off <<= 1) s2 += __shfl_xor(s2, off);
        mu[r] = m;
        rstd[r] = rsqrtf(s2 * (1.f / 256.f) + 1e-5f);
    }
    float* yrow = y + ((size_t)pair * L_ + m0) * C_;
#pragma unroll
    for (int u = 0; u < 16; ++u) {
        int col = u * 16 + l16;
        float g = gamma[col], be = beta[col];
#pragma unroll
        for (int r = 0; r < 4; ++r)
            yrow[(size_t)(quad * 4 + r) * C_ + col] =
                (acc[u][r] - mu[r]) * rstd[r] * g + be;
    }
}

// ---------------------------------------------------------------------------
// K4: y[pair, l, c] (f32) -> out[B,C,H,W] (f32)
// ---------------------------------------------------------------------------
__global__ __launch_bounds__(256) void k_merge(const float* __restrict__ y,
                                               float* __restrict__ out) {
    __shared__ float lds[32][257];
    int bid = blockIdx.x;
    int pair = bid >> 5, p = bid & 31;
    int b = pair >> 2, a = pair & 3, i = a >> 1, j = a & 1;
    int t = threadIdx.x;
    int q = t & 31, csub = t >> 5;
    const float* yr = y + ((size_t)pair * L_ + (size_t)p * 32) * C_;
    for (int r = 0; r < 32; ++r) {
        lds[r][t] = yr[(size_t)r * C_ + t];
    }
    __syncthreads();
    float* xb = out + (size_t)b * C_ * H_ * W_ + (size_t)(i * 32 + p) * W_ + j * 32;
    for (int r = 0; r < 32; ++r) {
        int c = r * 8 + csub;
        xb[(size_t)c * H_ * W_ + q] = lds[q][c];
    }
}

// ---------------------------------------------------------------------------
extern "C" void kernel_launch(void* const* d_in, const int* in_sizes, int n_in,
                              void* d_out, int out_size, void* d_ws, size_t ws_size,
                              hipStream_t stream) {
    (void)in_sizes; (void)n_in; (void)out_size; (void)ws_size;
    const float* x     = (const float*)d_in[0];
    const float* Win   = (const float*)d_in[1];
    const float* bin   = (const float*)d_in[2];
    const float* Wout  = (const float*)d_in[3];
    const float* bout  = (const float*)d_in[4];
    const float* gamma = (const float*)d_in[5];
    const float* beta  = (const float*)d_in[6];
    float* out = (float*)d_out;

    char* ws = (char*)d_ws;
    bf16* xa    = (bf16*)ws;                           // 16 MiB
    bf16* qkv   = (bf16*)(ws + ((size_t)16 << 20));    // 48 MiB
    bf16* o     = (bf16*)(ws + ((size_t)64 << 20));    // 16 MiB
    bf16* Winb  = (bf16*)(ws + ((size_t)80 << 20));    // 1.5 MiB
    bf16* Woutb = (bf16*)(ws + ((size_t)82 << 20));    // 0.5 MiB
    float* y    = (float*)(ws + ((size_t)16 << 20));   // 32 MiB, aliases dead qkv

    k_cvt<<<(NW4 + NO4 + 255) / 256, 256, 0, stream>>>(Win, Wout, Winb, Woutb);
    k_split<<<NPAIR * 32, 256, 0, stream>>>(x, xa);
    k_qkv<<<NPAIR * 16 * 6, 256, 0, stream>>>(xa, Winb, bin, qkv);
    k_attn<<<NPAIR * NH_ * 16, 256, 0, stream>>>(qkv, o);
    k_out<<<NPAIR * 16, 256, 0, stream>>>(o, Woutb, bout, xa, gamma, beta, y);
    k_merge<<<NPAIR * 32, 256, 0, stream>>>(y, out);
}